// Round 16
// baseline (72.826 us; speedup 1.0000x reference)
//
#include <hip/hip_runtime.h>
#include <hip/hip_fp16.h>
#include <cmath>

// Radon backprojection, TWO dispatches, atomic-free, 32 waves/CU:
//   1) pack: zero-padded fp16 (v[j-1],v[j]) pair table [A][PES] (4 batches
//      per 16B entry), pairwise (2 entries/thread), + trig table.
//   2) gather: 512-thread block per 64x2 pixel tile; 4 angle-groups x 128 px;
//      partials reduced in LDS (block-local barrier), plain stores.
//      grid=512 -> 4 blocks/CU = 32 waves/CU (vs R15's 16).
//
// R15 post-mortem: atomic removal ~neutral at ACHUNKS=4 (already hidden).
// Residual theory: at 16 waves/CU the gather loop is marginally latency-
// exposed (96 cyc issue vs ~200-300 cyc load latency per SIMD round).
// R16 doubles resident waves; v_med3_f32 clamp replaces the int clamp
// chain (border w irrelevant: entries are zero).

#define AGROUPS 4
#define TPX 128                        // pixels per tile (64x2)

typedef __fp16 half2v __attribute__((ext_vector_type(2)));

__device__ __forceinline__ half2v as_h2(unsigned u) {
    union { unsigned u; half2v h; } x; x.u = u; return x.h;
}

__global__ __launch_bounds__(256) void radon_pack(
    const float* __restrict__ sino,
    const float* __restrict__ thetas,
    const float* __restrict__ positions,
    uint4* __restrict__ packed,        // [A][PES]; entry j: (v[j-1], v[j]) x4
    float2* __restrict__ trig,         // [A+1]; trig[A].x = q0
    int A, int P, int PES, int bstride)
{
    const int gidx = blockIdx.x * 256 + threadIdx.x;   // pair index
    const int pairsPerA = PES >> 1;
    const int a  = gidx / pairsPerA;
    const int j0 = (gidx - a * pairsPerA) << 1;        // entries j0, j0+1
    if (a >= A) return;

    const float p0     = positions[0];
    const float inv_dp = 1.0f / (positions[1] - p0);
    if (j0 == 0) {
        float th = thetas[a];
        trig[a] = make_float2(cosf(th) * inv_dp, sinf(th) * inv_dp);
        if (a == 0) trig[A] = make_float2(-p0 * inv_dp, 0.0f);
    }

    uint4 e0 = make_uint4(0, 0, 0, 0);
    uint4 e1 = make_uint4(0, 0, 0, 0);
    unsigned* e0p = (unsigned*)&e0;
    unsigned* e1p = (unsigned*)&e1;
    const float* s = sino + (size_t)a * P;
#pragma unroll
    for (int b = 0; b < 4; ++b) {
        const float* sb = s + (size_t)b * bstride;
        // entries j0   -> (v[j0-1], v[j0])   valid if 1<=j0<=P-1
        //         j0+1 -> (v[j0],   v[j0+1]) valid if j0+1<=P-1
        float vm1 = (j0 >= 1 && j0 <= P - 1) ? sb[j0 - 1] : 0.f;
        float v0  = (j0 >= 1 && j0 <= P - 1) || (j0 + 1 <= P - 1) ?
                    ((j0 >= 0 && j0 <= P - 1) ? sb[j0] : 0.f) : 0.f;
        float v1  = (j0 + 1 >= 1 && j0 + 1 <= P - 1) ? sb[j0 + 1] : 0.f;
        if (j0 >= 1 && j0 <= P - 1) {
            union { half2v h; unsigned u; } c;
            c.h = __builtin_amdgcn_cvt_pkrtz(vm1, v0);
            e0p[b] = c.u;
        }
        if (j0 + 1 >= 1 && j0 + 1 <= P - 1) {
            union { half2v h; unsigned u; } c;
            c.h = __builtin_amdgcn_cvt_pkrtz(v0, v1);
            e1p[b] = c.u;
        }
    }
    packed[(size_t)a * PES + j0]     = e0;
    packed[(size_t)a * PES + j0 + 1] = e1;
}

__global__ __launch_bounds__(512) void radon_gather_red(
    const uint4* __restrict__ packed,  // [A][PES]
    const float2* __restrict__ trig,   // [A+1]
    float* __restrict__ out,           // [4][nn]
    int A, int P, int PES, int N, int chunk)
{
    __shared__ float red[AGROUPS][TPX][4];   // 8 KB

    const int tid = threadIdx.x;
    const int nn  = N * N;
    const int g   = tid >> 7;          // angle group 0..3
    const int p   = tid & (TPX - 1);   // tile-local pixel 0..127

    // 16x4... here: two waves cover the 64x2 tile; wave w covers 32x2?
    // Simple mapping: p = local pixel, tile is 64 wide x 2 tall.
    const int lx = p & 63;
    const int ly = p >> 6;             // 0..1
    const int tilesx = N >> 6;
    const int bx = blockIdx.x % tilesx;
    const int by = blockIdx.x / tilesx;
    const int x  = (bx << 6) + lx;
    const int y  = (by << 1) + ly;

    const int a0 = g * chunk;
    const int a1 = min(A, a0 + chunk);

    const float half = (float)(N - 1) * 0.5f;
    const float cx = (float)x - half;
    const float cy = half - (float)y;
    const float q0 = trig[A].x;        // uniform -> s_load
    const float fhi = (float)(P - 1);

    float acc0 = 0.f, acc1 = 0.f, acc2 = 0.f, acc3 = 0.f;

#pragma unroll 4
    for (int a = a0; a < a1; ++a) {
        float2 t  = trig[a];           // uniform -> s_load_dwordx2
        float f   = fmaf(cx, t.x, fmaf(cy, t.y, q0));
        // clamp to [-1, P-1]; border entries are zero so w's value is moot
        float fc  = fminf(fmaxf(f, -1.0f), fhi);       // v_med3_f32
        float i0f = floorf(fc);
        float w_  = fc - i0f;
        int   j   = (int)i0f + 1;

        half2v w2 = __builtin_amdgcn_cvt_pkrtz(1.0f - w_, w_);   // (om, wm)
        uint4 e = packed[(size_t)a * PES + j];      // global_load_dwordx4
        acc0 = __builtin_amdgcn_fdot2(as_h2(e.x), w2, acc0, false);
        acc1 = __builtin_amdgcn_fdot2(as_h2(e.y), w2, acc1, false);
        acc2 = __builtin_amdgcn_fdot2(as_h2(e.z), w2, acc2, false);
        acc3 = __builtin_amdgcn_fdot2(as_h2(e.w), w2, acc3, false);
    }

    red[g][p][0] = acc0;
    red[g][p][1] = acc1;
    red[g][p][2] = acc2;
    red[g][p][3] = acc3;
    __syncthreads();

    // Reduce: thread t -> (batch b2 = t>>7, pixel p2 = t&127).
    const int b2 = tid >> 7;
    const int p2 = tid & (TPX - 1);
    float s = red[0][p2][b2] + red[1][p2][b2]
            + red[2][p2][b2] + red[3][p2][b2];

    const int x2 = (bx << 6) + (p2 & 63);
    const int y2 = (by << 1) + (p2 >> 6);
    out[(size_t)b2 * nn + y2 * N + x2] = s;
}

// Generic fallback: direct per-batch kernel (any shape).
__global__ __launch_bounds__(256) void radon_direct_kernel(
    const float* __restrict__ sino,
    const float* __restrict__ thetas,
    const float* __restrict__ positions,
    float* __restrict__ out,
    int A, int P, int N, int BC)
{
    const int nn  = N * N;
    const int pix = blockIdx.x * blockDim.x + threadIdx.x;
    if (pix >= nn) return;
    const float p0     = positions[0];
    const float inv_dp = 1.0f / (positions[1] - p0);
    const int x = pix % N;
    const int y = pix / N;
    const float half = (float)(N - 1) * 0.5f;
    const float cx = (float)x - half;
    const float cy = half - (float)y;
    for (int b = 0; b < BC; ++b) {
        float acc = 0.0f;
        for (int a = 0; a < A; ++a) {
            float th = thetas[a];
            float f  = (cx * cosf(th) + cy * sinf(th) - p0) * inv_dp;
            float i0f = floorf(f);
            int i0 = (int)i0f;
            float w = f - i0f;
            float m = (i0 >= 0 && i0 <= P - 2) ? 1.0f : 0.0f;
            int ic = min(max(i0, 0), P - 2);
            const float* row = sino + ((size_t)b * A + a) * P + ic;
            acc = fmaf(m, fmaf(w, row[1] - row[0], row[0]), acc);
        }
        out[(size_t)b * nn + pix] = acc;
    }
}

extern "C" void kernel_launch(void* const* d_in, const int* in_sizes, int n_in,
                              void* d_out, int out_size, void* d_ws, size_t ws_size,
                              hipStream_t stream) {
    const float* sino      = (const float*)d_in[0];
    const float* thetas    = (const float*)d_in[1];
    const float* positions = (const float*)d_in[2];
    float* out             = (float*)d_out;

    const int A  = in_sizes[1];               // 180
    const int P  = in_sizes[2];               // 384
    const int BC = in_sizes[0] / (A * P);     // B*C = 4
    const int N  = (int)lroundf(sqrtf((float)(out_size / BC)));
    const int nn = N * N;
    const int bstride = A * P;

    const int PES   = (P + 2 + 63) & ~63;     // padded entries per angle (even)
    const int chunk = (A + AGROUPS - 1) / AGROUPS;

    const size_t packed_bytes = (size_t)A * PES * sizeof(uint4);
    const size_t trig_bytes   = (size_t)(A + 1) * sizeof(float2);
    const size_t need = packed_bytes + trig_bytes;

    const bool fast = (BC == 4) && (A <= 1024) && (P >= 2)
                   && (N % 64 == 0) && ((N & 1) == 0) && (ws_size >= need);

    if (fast) {
        uint4*  packed = (uint4*)d_ws;
        float2* trig   = (float2*)((char*)d_ws + packed_bytes);

        dim3 block(256);
        const int pairs = A * (PES >> 1);
        dim3 gpack(((unsigned)pairs + 255) / 256);
        radon_pack<<<gpack, block, 0, stream>>>(
            sino, thetas, positions, packed, trig, A, P, PES, bstride);

        dim3 gblock(512);
        dim3 ggat((N / 64) * (N / 2));
        radon_gather_red<<<ggat, gblock, 0, stream>>>(
            packed, trig, out, A, P, PES, N, chunk);
    } else {
        dim3 block(256);
        dim3 grid((nn + 255) / 256);
        radon_direct_kernel<<<grid, block, 0, stream>>>(
            sino, thetas, positions, out, A, P, N, BC);
    }
}

// Round 17
// 71.284 us; speedup vs baseline: 1.0216x; 1.0216x over previous
//
#include <hip/hip_runtime.h>
#include <hip/hip_fp16.h>
#include <cmath>

// Radon backprojection, TWO dispatches, atomic-free (R15 config = measured
// best, 70.885 us):
//   1) pack: zero-padded fp16 (v[j-1],v[j]) pair table [A][PES] (4 batches
//      per 16B entry) + trig table.
//   2) gather: one 1024-thread block (16 waves) per 64x4 pixel tile; the 4
//      wave-groups split the angle range 4 ways; partials reduced in LDS
//      (one barrier, block-local only) and committed with plain stores.
//
// Ladder summary (R1->R16, 130 -> 70.9 us):
//  - occupancy via angle-chunking (R2): 1 wave/SIMD is a ~4x cliff; >=16
//    waves/CU suffices (R16 showed 32 is NOT better: loop is issue-bound).
//  - repack to one dwordx4 gather + fdot2 per pixel-angle (R6-R10): the
//    per-CU vmem/LDS issue count is the real cost; branchless vs branchy,
//    atomic vs store epilogues are ~neutral.
//  - no per-angle __syncthreads (R7, -6us): compiler drains vmcnt(0) at
//    barriers.
//  - NEVER per-block __threadfence on MI355X (R11: +150us L2 flush storm
//    across 8 XCDs). Plain device-scope atomicAdd is safe (R12).
//  - Remaining dur_us is ~49us harness fill/restore floor + 2 launches +
//    issue-bound gather (~21us total ours).

#define AGROUPS 4

typedef __fp16 half2v __attribute__((ext_vector_type(2)));

__device__ __forceinline__ half2v as_h2(unsigned u) {
    union { unsigned u; half2v h; } x; x.u = u; return x.h;
}

__global__ __launch_bounds__(256) void radon_pack(
    const float* __restrict__ sino,
    const float* __restrict__ thetas,
    const float* __restrict__ positions,
    uint4* __restrict__ packed,        // [A][PES]; entry j: (v[j-1], v[j]) x4
    float2* __restrict__ trig,         // [A+1]; trig[A].x = q0
    int A, int P, int PES, int bstride)
{
    const int gidx = blockIdx.x * 256 + threadIdx.x;
    const int a = gidx / PES;
    const int j = gidx - a * PES;
    if (a >= A) return;

    const float p0     = positions[0];
    const float inv_dp = 1.0f / (positions[1] - p0);
    if (j == 0) {
        float th = thetas[a];
        trig[a] = make_float2(cosf(th) * inv_dp, sinf(th) * inv_dp);
        if (a == 0) trig[A] = make_float2(-p0 * inv_dp, 0.0f);
    }

    uint4 e = make_uint4(0, 0, 0, 0);
    if (j >= 1 && j <= P - 1) {
        const float* s = sino + (size_t)a * P + (j - 1);
        unsigned* ep = (unsigned*)&e;
#pragma unroll
        for (int b = 0; b < 4; ++b) {
            float2 v = *(const float2*)(s + (size_t)b * bstride); // dwordx2
            half2v h = __builtin_amdgcn_cvt_pkrtz(v.x, v.y);      // lo=v0 hi=v1
            union { half2v h; unsigned u; } cvt; cvt.h = h;
            ep[b] = cvt.u;
        }
    }
    packed[(size_t)a * PES + j] = e;
}

__global__ __launch_bounds__(1024) void radon_gather_red(
    const uint4* __restrict__ packed,  // [A][PES]
    const float2* __restrict__ trig,   // [A+1]
    float* __restrict__ out,           // [4][nn]
    int A, int P, int PES, int N, int chunk)
{
    __shared__ float red[AGROUPS][256][4];   // 16 KB

    const int tid = threadIdx.x;
    const int nn  = N * N;
    const int g   = tid >> 8;          // angle group 0..3
    const int p   = tid & 255;         // tile-local pixel 0..255

    // 16x4 wave tiling of the 64x4 tile.
    const int w  = p >> 6;             // wave-tile 0..3
    const int l  = p & 63;
    const int lx = l & 15;
    const int ly = l >> 4;
    const int tilesx = N >> 6;
    const int bx = blockIdx.x % tilesx;
    const int by = blockIdx.x / tilesx;
    const int x  = (bx << 6) + (w << 4) + lx;
    const int y  = (by << 2) + ly;

    const int a0 = g * chunk;
    const int a1 = min(A, a0 + chunk);

    const float half = (float)(N - 1) * 0.5f;
    const float cx = (float)x - half;
    const float cy = half - (float)y;
    const float q0 = trig[A].x;        // uniform -> s_load

    float acc0 = 0.f, acc1 = 0.f, acc2 = 0.f, acc3 = 0.f;

#pragma unroll 4
    for (int a = a0; a < a1; ++a) {
        float2 t  = trig[a];           // uniform -> s_load_dwordx2
        float f   = fmaf(cx, t.x, fmaf(cy, t.y, q0));
        float i0f = floorf(f);
        float w_  = f - i0f;
        int   i0  = (int)i0f;
        int   j   = min(max(i0, -1), P - 1) + 1;   // borders -> zero entries

        half2v w2 = __builtin_amdgcn_cvt_pkrtz(1.0f - w_, w_);   // (om, wm)
        uint4 e = packed[(size_t)a * PES + j];      // global_load_dwordx4
        acc0 = __builtin_amdgcn_fdot2(as_h2(e.x), w2, acc0, false);
        acc1 = __builtin_amdgcn_fdot2(as_h2(e.y), w2, acc1, false);
        acc2 = __builtin_amdgcn_fdot2(as_h2(e.z), w2, acc2, false);
        acc3 = __builtin_amdgcn_fdot2(as_h2(e.w), w2, acc3, false);
    }

    // ds_write_b128: this group's 4-batch partial for pixel p.
    red[g][p][0] = acc0;
    red[g][p][1] = acc1;
    red[g][p][2] = acc2;
    red[g][p][3] = acc3;
    __syncthreads();

    // Reduce phase: thread t -> (batch b2 = t>>8, pixel p2 = t&255).
    const int b2 = tid >> 8;
    const int p2 = tid & 255;
    float s = red[0][p2][b2] + red[1][p2][b2]
            + red[2][p2][b2] + red[3][p2][b2];

    const int w2_ = p2 >> 6;
    const int l2  = p2 & 63;
    const int x2  = (bx << 6) + (w2_ << 4) + (l2 & 15);
    const int y2  = (by << 2) + (l2 >> 4);
    out[(size_t)b2 * nn + y2 * N + x2] = s;
}

// Generic fallback: direct per-batch kernel (any shape).
__global__ __launch_bounds__(256) void radon_direct_kernel(
    const float* __restrict__ sino,
    const float* __restrict__ thetas,
    const float* __restrict__ positions,
    float* __restrict__ out,
    int A, int P, int N, int BC)
{
    const int nn  = N * N;
    const int pix = blockIdx.x * blockDim.x + threadIdx.x;
    if (pix >= nn) return;
    const float p0     = positions[0];
    const float inv_dp = 1.0f / (positions[1] - p0);
    const int x = pix % N;
    const int y = pix / N;
    const float half = (float)(N - 1) * 0.5f;
    const float cx = (float)x - half;
    const float cy = half - (float)y;
    for (int b = 0; b < BC; ++b) {
        float acc = 0.0f;
        for (int a = 0; a < A; ++a) {
            float th = thetas[a];
            float f  = (cx * cosf(th) + cy * sinf(th) - p0) * inv_dp;
            float i0f = floorf(f);
            int i0 = (int)i0f;
            float w = f - i0f;
            float m = (i0 >= 0 && i0 <= P - 2) ? 1.0f : 0.0f;
            int ic = min(max(i0, 0), P - 2);
            const float* row = sino + ((size_t)b * A + a) * P + ic;
            acc = fmaf(m, fmaf(w, row[1] - row[0], row[0]), acc);
        }
        out[(size_t)b * nn + pix] = acc;
    }
}

extern "C" void kernel_launch(void* const* d_in, const int* in_sizes, int n_in,
                              void* d_out, int out_size, void* d_ws, size_t ws_size,
                              hipStream_t stream) {
    const float* sino      = (const float*)d_in[0];
    const float* thetas    = (const float*)d_in[1];
    const float* positions = (const float*)d_in[2];
    float* out             = (float*)d_out;

    const int A  = in_sizes[1];               // 180
    const int P  = in_sizes[2];               // 384
    const int BC = in_sizes[0] / (A * P);     // B*C = 4
    const int N  = (int)lroundf(sqrtf((float)(out_size / BC)));
    const int nn = N * N;
    const int bstride = A * P;

    const int PES   = (P + 2 + 63) & ~63;     // padded entries per angle
    const int chunk = (A + AGROUPS - 1) / AGROUPS;

    const size_t packed_bytes = (size_t)A * PES * sizeof(uint4);
    const size_t trig_bytes   = (size_t)(A + 1) * sizeof(float2);
    const size_t need = packed_bytes + trig_bytes;

    const bool fast = (BC == 4) && (A <= 1024) && (P >= 2)
                   && (N % 64 == 0) && (ws_size >= need);

    if (fast) {
        uint4*  packed = (uint4*)d_ws;
        float2* trig   = (float2*)((char*)d_ws + packed_bytes);

        dim3 block(256);
        dim3 gpack(((unsigned)(A * PES) + 255) / 256);
        radon_pack<<<gpack, block, 0, stream>>>(
            sino, thetas, positions, packed, trig, A, P, PES, bstride);

        dim3 gblock(1024);
        dim3 ggat((N / 64) * (N / 4));
        radon_gather_red<<<ggat, gblock, 0, stream>>>(
            packed, trig, out, A, P, PES, N, chunk);
    } else {
        dim3 block(256);
        dim3 grid((nn + 255) / 256);
        radon_direct_kernel<<<grid, block, 0, stream>>>(
            sino, thetas, positions, out, A, P, N, BC);
    }
}